// Round 2
// baseline (1754.776 us; speedup 1.0000x reference)
//
#include <hip/hip_runtime.h>
#include <math.h>

// ---------------- problem constants ----------------
constexpr int Lc = 4, Bc = 16, Sc = 512, Hc = 768, NHc = 12, FFc = 3072, Dc = 64;
constexpr int MR = Bc * Sc;            // 8192 token rows
constexpr int QS = 2304;               // fused QKV row stride
constexpr float SCALEc = 0.125f;       // D^-0.5

typedef __attribute__((ext_vector_type(8))) __bf16 bf16x8;
typedef __attribute__((ext_vector_type(4))) __bf16 bf16x4;
typedef __attribute__((ext_vector_type(4))) float  floatx4;

__device__ inline floatx4 mfma16(bf16x8 a, bf16x8 b, floatx4 c) {
    return __builtin_amdgcn_mfma_f32_16x16x32_bf16(a, b, c, 0, 0, 0);
}
__device__ inline float gelu_f(float x) {
    return 0.5f * x * (1.0f + erff(x * 0.70710678118654752f));
}
// async global->LDS, 16B per lane; LDS dest = wave-uniform base + lane*16
__device__ inline void ld16(const __bf16* g, __bf16* l) {
    __builtin_amdgcn_global_load_lds(
        (const __attribute__((address_space(1))) void*)g,
        (__attribute__((address_space(3))) void*)l, 16, 0, 0);
}

// ---------------- LayerNorm: one wave per row ----------
template<bool FINAL>
__global__ __launch_bounds__(256) void ln_k(
    const float* __restrict__ x, const float* __restrict__ g, const float* __restrict__ bt,
    __bf16* __restrict__ yb, float* __restrict__ yf)
{
    const int row  = blockIdx.x * 4 + (threadIdx.x >> 6);
    const int lane = threadIdx.x & 63;
    const int col  = lane * 12;
    const float* xr = x + (size_t)row * Hc + col;
    float v[12];
    *(float4*)(v + 0) = *(const float4*)(xr + 0);
    *(float4*)(v + 4) = *(const float4*)(xr + 4);
    *(float4*)(v + 8) = *(const float4*)(xr + 8);
    float s = 0.f, s2 = 0.f;
#pragma unroll
    for (int j = 0; j < 12; ++j) { s += v[j]; s2 += v[j] * v[j]; }
#pragma unroll
    for (int o = 32; o > 0; o >>= 1) { s += __shfl_xor(s, o); s2 += __shfl_xor(s2, o); }
    const float mean = s * (1.0f / Hc);
    const float inv  = rsqrtf(s2 * (1.0f / Hc) - mean * mean + 1e-5f);
    float gv[12], bv[12];
    *(float4*)(gv + 0) = *(const float4*)(g + col);
    *(float4*)(gv + 4) = *(const float4*)(g + col + 4);
    *(float4*)(gv + 8) = *(const float4*)(g + col + 8);
    *(float4*)(bv + 0) = *(const float4*)(bt + col);
    *(float4*)(bv + 4) = *(const float4*)(bt + col + 4);
    *(float4*)(bv + 8) = *(const float4*)(bt + col + 8);
    if (FINAL) {
        float o[12];
#pragma unroll
        for (int j = 0; j < 12; ++j) o[j] = (v[j] - mean) * inv * gv[j] + bv[j];
        float* yr = yf + (size_t)row * Hc + col;
        *(float4*)(yr + 0) = *(float4*)(o + 0);
        *(float4*)(yr + 4) = *(float4*)(o + 4);
        *(float4*)(yr + 8) = *(float4*)(o + 8);
    } else {
        __bf16 o[12];
#pragma unroll
        for (int j = 0; j < 12; ++j) o[j] = (__bf16)((v[j] - mean) * inv * gv[j] + bv[j]);
        __bf16* yr = yb + (size_t)row * Hc + col;
        *(bf16x4*)(yr + 0) = *(bf16x4*)(o + 0);
        *(bf16x4*)(yr + 4) = *(bf16x4*)(o + 4);
        *(bf16x4*)(yr + 8) = *(bf16x4*)(o + 8);
    }
}

// ---------------- unified per-layer weight prep ----------------
__global__ __launch_bounds__(256) void prep_k(
    const float* __restrict__ wq, const float* __restrict__ wk,
    const float* __restrict__ wv, const float* __restrict__ wo,
    const float* __restrict__ w1, const float* __restrict__ w2,
    const float* __restrict__ bq, const float* __restrict__ bk, const float* __restrict__ bv,
    __bf16* __restrict__ wqkvt, __bf16* __restrict__ wot,
    __bf16* __restrict__ w1t, __bf16* __restrict__ w2t, float* __restrict__ bqkv)
{
    const int id = blockIdx.x;
    if (id >= 6912) {                      // bias concat
        int i = (id - 6912) * 256 + threadIdx.x;
        if (i < QS) bqkv[i] = i < Hc ? bq[i] : (i < 2 * Hc ? bk[i - Hc] : bv[i - 2 * Hc]);
        return;
    }
    const float* in; __bf16* out; int R, C, tile;
    if (id < 2304) {
        int piece = id / 576; tile = id % 576; R = Hc; C = Hc;
        in  = piece == 0 ? wq : piece == 1 ? wk : piece == 2 ? wv : wo;
        out = piece == 3 ? wot : wqkvt + (size_t)piece * Hc * Hc;
    } else if (id < 4608) {
        tile = id - 2304; R = Hc; C = FFc; in = w1; out = w1t;
    } else {
        tile = id - 4608; R = FFc; C = Hc; in = w2; out = w2t;
    }
    const int nx = C / 32;
    const int bx = tile % nx, by = tile / nx;
    __shared__ float t[32][33];
    const int c0 = bx * 32, r0 = by * 32;
    const int tx = threadIdx.x & 31, ty = threadIdx.x >> 5;   // 32 x 8
#pragma unroll
    for (int i2 = 0; i2 < 4; ++i2)
        t[ty + i2 * 8][tx] = in[(size_t)(r0 + ty + i2 * 8) * C + c0 + tx];
    __syncthreads();
#pragma unroll
    for (int i2 = 0; i2 < 4; ++i2)
        out[(size_t)(c0 + ty + i2 * 8) * R + r0 + tx] = (__bf16)t[tx][ty + i2 * 8];
}

// ---------------- GEMM 128x128 (4 waves): for wide-N gemms (QKV, FFN1) --------
template<int ACT, bool RESID>
__global__ __launch_bounds__(256) void gemm2_k(
    const __bf16* __restrict__ A, const __bf16* __restrict__ Bt,
    const float* __restrict__ bias, const float* __restrict__ resid,
    float* __restrict__ outF, __bf16* __restrict__ outB,
    int M, int N, int K)
{
    __shared__ alignas(16) __bf16 As[128 * 32];
    __shared__ alignas(16) __bf16 Bs[128 * 32];
    const int tid  = threadIdx.x;
    const int wave = tid >> 6, lane = tid & 63, lhi = lane >> 4, llo = lane & 15;
    const int wm = wave >> 1, wn = wave & 1;
    const int row0 = blockIdx.y * 128, col0 = blockIdx.x * 128;
    const int srow = lane >> 2;            // 0..15
    const int scol = (lane & 3) * 8;       // 0,8,16,24

    floatx4 acc[4][4];
#pragma unroll
    for (int i = 0; i < 4; ++i)
#pragma unroll
        for (int j = 0; j < 4; ++j) acc[i][j] = {0.f, 0.f, 0.f, 0.f};

    const __bf16* Ab = A  + (size_t)(row0 + wave * 16 + srow) * K + scol;
    const __bf16* Bb = Bt + (size_t)(col0 + wave * 16 + srow) * K + scol;

    for (int kt = 0; kt < K; kt += 32) {
#pragma unroll
        for (int t = 0; t < 2; ++t) {
            ld16(Ab + (size_t)(t * 64) * K + kt, As + (t * 64 + wave * 16) * 32);
            ld16(Bb + (size_t)(t * 64) * K + kt, Bs + (t * 64 + wave * 16) * 32);
        }
        __syncthreads();
        bf16x8 af[4], bfr[4];
#pragma unroll
        for (int i = 0; i < 4; ++i)
            af[i]  = *(const bf16x8*)(As + (wm * 64 + i * 16 + llo) * 32 + lhi * 8);
#pragma unroll
        for (int j = 0; j < 4; ++j)
            bfr[j] = *(const bf16x8*)(Bs + (wn * 64 + j * 16 + llo) * 32 + lhi * 8);
#pragma unroll
        for (int i = 0; i < 4; ++i)
#pragma unroll
            for (int j = 0; j < 4; ++j)
                acc[i][j] = mfma16(af[i], bfr[j], acc[i][j]);
        __syncthreads();
    }
#pragma unroll
    for (int i = 0; i < 4; ++i) {
#pragma unroll
        for (int j = 0; j < 4; ++j) {
            int colc = col0 + wn * 64 + j * 16 + llo;
            float bb = bias[colc];
#pragma unroll
            for (int r = 0; r < 4; ++r) {
                int rowc = row0 + wm * 64 + i * 16 + lhi * 4 + r;
                float vv = acc[i][j][r] + bb;
                if (ACT == 1) vv = gelu_f(vv);
                size_t idx = (size_t)rowc * N + colc;
                if (RESID) outF[idx] = resid[idx] + vv;
                else       outB[idx] = (__bf16)vv;
            }
        }
    }
}

// ---------------- GEMM 128x64 split-K (4 waves): N=768 resid gemms ------------
// v2: grid is only 768 blocks (N=768) -> with 2-wave blocks that was 6 waves/CU
// (1.5/SIMD): nobody to hide the per-K-step vmcnt(0)+barrier drain behind.
// Now 4 waves/block: wave pair p in {0,1} computes the whole 128x64 tile over
// K-half p (half-length K loop), epilogue combines via LDS. 12 waves/CU.
// LDS: union of staging (24.0 KB) and reduce buffer Rs 128x66 fp32 (33.8 KB)
// -> 33.8 KB, 4 blocks/CU LDS-max (grid-limited at 3). Rs stride 66: write/read
// pattern hits each bank exactly 2x (2-way = free, m136).
__global__ __launch_bounds__(256) void gemm3_k(
    const __bf16* __restrict__ A, const __bf16* __restrict__ Bt,
    const float* __restrict__ bias, const float* __restrict__ resid,
    float* __restrict__ outF, int M, int N, int K)
{
    __shared__ alignas(16) unsigned char smem[33792];
    __bf16* As = (__bf16*)smem;            // [2][128][32]
    __bf16* Bs = As + 2 * 128 * 32;        // [2][64][32]
    float*  Rs = (float*)smem;             // [128][66] (epilogue only)

    const int tid  = threadIdx.x;
    const int wave = tid >> 6, lane = tid & 63, lhi = lane >> 4, llo = lane & 15;
    const int pair = wave >> 1;            // K-half index
    const int wrow = wave & 1;             // row-half index for staging / rows
    const int row0 = blockIdx.y * 128, col0 = blockIdx.x * 64;
    const int srow = lane >> 2;            // 0..15
    const int scol = (lane & 3) * 8;       // 0,8,16,24
    const int Kh   = K >> 1;

    floatx4 acc[4][4];
#pragma unroll
    for (int i = 0; i < 4; ++i)
#pragma unroll
        for (int j = 0; j < 4; ++j) acc[i][j] = {0.f, 0.f, 0.f, 0.f};

    // each wave stages its pair's K-half: A rows [wrow*64, +64), B rows [wrow*32, +32)
    const __bf16* Ab = A  + (size_t)(row0 + wrow * 64 + srow) * K + (size_t)pair * Kh + scol;
    const __bf16* Bb = Bt + (size_t)(col0 + wrow * 32 + srow) * K + (size_t)pair * Kh + scol;
    __bf16* AsP = As + pair * (128 * 32);
    __bf16* BsP = Bs + pair * (64 * 32);

    for (int kt = 0; kt < Kh; kt += 32) {
#pragma unroll
        for (int t = 0; t < 4; ++t)
            ld16(Ab + (size_t)(t * 16) * K + kt, AsP + (wrow * 64 + t * 16) * 32);
#pragma unroll
        for (int t = 0; t < 2; ++t)
            ld16(Bb + (size_t)(t * 16) * K + kt, BsP + (wrow * 32 + t * 16) * 32);
        __syncthreads();
        bf16x8 af[4], bfr[4];
#pragma unroll
        for (int i = 0; i < 4; ++i)
            af[i]  = *(const bf16x8*)(AsP + (wrow * 64 + i * 16 + llo) * 32 + lhi * 8);
#pragma unroll
        for (int j = 0; j < 4; ++j)
            bfr[j] = *(const bf16x8*)(BsP + (j * 16 + llo) * 32 + lhi * 8);
#pragma unroll
        for (int i = 0; i < 4; ++i)
#pragma unroll
            for (int j = 0; j < 4; ++j)
                acc[i][j] = mfma16(af[i], bfr[j], acc[i][j]);
        __syncthreads();
    }

    // ---- combine K-halves: pair 1 -> LDS, pair 0 adds + epilogue ----
    if (pair == 1) {
#pragma unroll
        for (int i = 0; i < 4; ++i)
#pragma unroll
            for (int j = 0; j < 4; ++j)
#pragma unroll
                for (int r = 0; r < 4; ++r)
                    Rs[(wrow * 64 + i * 16 + lhi * 4 + r) * 66 + j * 16 + llo] = acc[i][j][r];
    }
    __syncthreads();
    if (pair == 0) {
#pragma unroll
        for (int i = 0; i < 4; ++i) {
#pragma unroll
            for (int j = 0; j < 4; ++j) {
                int colc = col0 + j * 16 + llo;
                float bb = bias[colc];
#pragma unroll
                for (int r = 0; r < 4; ++r) {
                    int rloc = wrow * 64 + i * 16 + lhi * 4 + r;
                    int rowc = row0 + rloc;
                    float vv = acc[i][j][r] + Rs[rloc * 66 + j * 16 + llo] + bb;
                    size_t idx = (size_t)rowc * N + colc;
                    outF[idx] = resid[idx] + vv;
                }
            }
        }
    }
}

// ---------------- Flash attention (v2) ----------------
__global__ __launch_bounds__(256) void attn_k(
    const __bf16* __restrict__ q, const __bf16* __restrict__ k,
    const __bf16* __restrict__ v, const float* __restrict__ bias,
    __bf16* __restrict__ o)
{
    __shared__ alignas(16) __bf16 QPs[64][72];     // Q staging, then P tiles
    __shared__ alignas(16) __bf16 Ks[2][64][72];
    __shared__ alignas(16) __bf16 Vt[2][64][66];   // [d][t], stride 66

    const int hh = blockIdx.x % NHc, b = blockIdx.x / NHc, qt = blockIdx.y;
    const int tid = threadIdx.x, wave = tid >> 6, lane = tid & 63;
    const int lhi = lane >> 4, llo = lane & 15;
    const size_t base  = (size_t)b * Sc * QS + hh * Dc;   // qkv addressing
    const size_t obase = (size_t)b * Sc * Hc + hh * Dc;   // output addressing

    const int sr0 = tid >> 3;          // 0..31 (and +32 for 2nd chunk)
    const int sc0 = (tid & 7) * 8;     // 0..56

    // ---- prologue: stage Q and tile-0 K/V
    {
        bf16x8 q0 = *(const bf16x8*)(q + base + (size_t)(qt * 64 + sr0) * QS + sc0);
        bf16x8 q1 = *(const bf16x8*)(q + base + (size_t)(qt * 64 + sr0 + 32) * QS + sc0);
        *(bf16x8*)(&QPs[sr0][sc0])      = q0;
        *(bf16x8*)(&QPs[sr0 + 32][sc0]) = q1;
        bf16x8 k0 = *(const bf16x8*)(k + base + (size_t)(sr0) * QS + sc0);
        bf16x8 k1 = *(const bf16x8*)(k + base + (size_t)(sr0 + 32) * QS + sc0);
        *(bf16x8*)(&Ks[0][sr0][sc0])      = k0;
        *(bf16x8*)(&Ks[0][sr0 + 32][sc0]) = k1;
        bf16x8 v0 = *(const bf16x8*)(v + base + (size_t)(sr0) * QS + sc0);
        bf16x8 v1 = *(const bf16x8*)(v + base + (size_t)(sr0 + 32) * QS + sc0);
#pragma unroll
        for (int jj = 0; jj < 8; ++jj) {
            Vt[0][sc0 + jj][sr0]      = v0[jj];
            Vt[0][sc0 + jj][sr0 + 32] = v1[jj];
        }
    }
    __syncthreads();

    // Q fragments -> registers (QPs becomes free for Ps reuse; wave-local)
    bf16x8 aq0 = *(const bf16x8*)(&QPs[wave * 16 + llo][0 * 32 + lhi * 8]);
    bf16x8 aq1 = *(const bf16x8*)(&QPs[wave * 16 + llo][1 * 32 + lhi * 8]);

    float m_reg[4], l_reg[4];
#pragma unroll
    for (int r = 0; r < 4; ++r) { m_reg[r] = -1e30f; l_reg[r] = 0.f; }

    floatx4 acco[4];
#pragma unroll
    for (int j = 0; j < 4; ++j) acco[j] = {0.f, 0.f, 0.f, 0.f};

    const float* brow = bias + ((size_t)(b * NHc + hh) * Sc + qt * 64) * Sc;

    // bias prefetch for tile 0
    float bnx[4][4];
#pragma unroll
    for (int nf = 0; nf < 4; ++nf)
#pragma unroll
        for (int r = 0; r < 4; ++r)
            bnx[nf][r] = brow[(size_t)(wave * 16 + lhi * 4 + r) * Sc + nf * 16 + llo];

    for (int it = 0; it < 8; ++it) {
        const int cur = it & 1;
        // 1) issue next-tile K/V global loads (consumed at step 6)
        bf16x8 k0, k1, v0, v1;
        if (it < 7) {
            const int ktn = (it + 1) * 64;
            k0 = *(const bf16x8*)(k + base + (size_t)(ktn + sr0) * QS + sc0);
            k1 = *(const bf16x8*)(k + base + (size_t)(ktn + sr0 + 32) * QS + sc0);
            v0 = *(const bf16x8*)(v + base + (size_t)(ktn + sr0) * QS + sc0);
            v1 = *(const bf16x8*)(v + base + (size_t)(ktn + sr0 + 32) * QS + sc0);
        }
        // 2) QK^T on buffer cur
        floatx4 accs[4];
#pragma unroll
        for (int j = 0; j < 4; ++j) accs[j] = {0.f, 0.f, 0.f, 0.f};
#pragma unroll
        for (int nf = 0; nf < 4; ++nf) {
            bf16x8 bk2 = *(const bf16x8*)(&Ks[cur][nf * 16 + llo][lhi * 8]);
            accs[nf] = mfma16(aq0, bk2, accs[nf]);
        }
#pragma unroll
        for (int nf = 0; nf < 4; ++nf) {
            bf16x8 bk2 = *(const bf16x8*)(&Ks[cur][nf * 16 + llo][32 + lhi * 8]);
            accs[nf] = mfma16(aq1, bk2, accs[nf]);
        }
        // 3) scores = acc*scale + bias (consumes bnx for THIS tile)
        float sv[4][4];
#pragma unroll
        for (int nf = 0; nf < 4; ++nf)
#pragma unroll
            for (int r = 0; r < 4; ++r)
                sv[nf][r] = accs[nf][r] * SCALEc + bnx[nf][r];
        // 4) prefetch bias for next tile (registers now free)
        if (it < 7) {
            const int ktn = (it + 1) * 64;
#pragma unroll
            for (int nf = 0; nf < 4; ++nf)
#pragma unroll
                for (int r = 0; r < 4; ++r)
                    bnx[nf][r] = brow[(size_t)(wave * 16 + lhi * 4 + r) * Sc + ktn + nf * 16 + llo];
        }
        // 5) in-register online softmax (rows live in 16-lane llo groups)
        float al[4];
#pragma unroll
        for (int r = 0; r < 4; ++r) {
            float mx = fmaxf(fmaxf(sv[0][r], sv[1][r]), fmaxf(sv[2][r], sv[3][r]));
            mx = fmaxf(mx, __shfl_xor(mx, 1));
            mx = fmaxf(mx, __shfl_xor(mx, 2));
            mx = fmaxf(mx, __shfl_xor(mx, 4));
            mx = fmaxf(mx, __shfl_xor(mx, 8));
            float mnew = fmaxf(m_reg[r], mx);
            al[r] = __expf(m_reg[r] - mnew);
            m_reg[r] = mnew;
            float sum = 0.f;
#pragma unroll
            for (int nf = 0; nf < 4; ++nf) {
                float p = __expf(sv[nf][r] - mnew);
                sum += p;
                QPs[wave * 16 + lhi * 4 + r][nf * 16 + llo] = (__bf16)p;  // wave-local
            }
            sum += __shfl_xor(sum, 1);
            sum += __shfl_xor(sum, 2);
            sum += __shfl_xor(sum, 4);
            sum += __shfl_xor(sum, 8);
            l_reg[r] = l_reg[r] * al[r] + sum;
        }
        // rescale running O
#pragma unroll
        for (int nf = 0; nf < 4; ++nf)
#pragma unroll
            for (int r = 0; r < 4; ++r) acco[nf][r] *= al[r];
        // PV on buffer cur (Ps wave-local: in-order DS per wave, no barrier)
#pragma unroll
        for (int kk = 0; kk < 2; ++kk) {
            bf16x8 ap = *(const bf16x8*)(&QPs[wave * 16 + llo][kk * 32 + lhi * 8]);
#pragma unroll
            for (int nf = 0; nf < 4; ++nf) {
                bf16x8 bv2 = *(const bf16x8*)(&Vt[cur][nf * 16 + llo][kk * 32 + lhi * 8]);
                acco[nf] = mfma16(ap, bv2, acco[nf]);
            }
        }
        // 6) write next-tile K/V into buffer cur^1
        if (it < 7) {
            *(bf16x8*)(&Ks[cur ^ 1][sr0][sc0])      = k0;
            *(bf16x8*)(&Ks[cur ^ 1][sr0 + 32][sc0]) = k1;
#pragma unroll
            for (int jj = 0; jj < 8; ++jj) {
                Vt[cur ^ 1][sc0 + jj][sr0]      = v0[jj];
                Vt[cur ^ 1][sc0 + jj][sr0 + 32] = v1[jj];
            }
        }
        // 7) single barrier per tile
        __syncthreads();
    }
#pragma unroll
    for (int nf = 0; nf < 4; ++nf) {
#pragma unroll
        for (int r = 0; r < 4; ++r) {
            int lr = wave * 16 + lhi * 4 + r;
            float oo = acco[nf][r] / l_reg[r];
            o[obase + (size_t)(qt * 64 + lr) * Hc + nf * 16 + llo] = (__bf16)oo;
        }
    }
}

// ---------------- orchestration ----------------
extern "C" void kernel_launch(void* const* d_in, const int* in_sizes, int n_in,
                              void* d_out, int out_size, void* d_ws, size_t ws_size,
                              hipStream_t stream)
{
    const float* x     = (const float*)d_in[0];
    const float* abias = (const float*)d_in[1];
    const float* ln1g  = (const float*)d_in[2];
    const float* ln1b  = (const float*)d_in[3];
    const float* wq    = (const float*)d_in[4];
    const float* bq    = (const float*)d_in[5];
    const float* wk    = (const float*)d_in[6];
    const float* bk    = (const float*)d_in[7];
    const float* wv    = (const float*)d_in[8];
    const float* bv    = (const float*)d_in[9];
    const float* wo    = (const float*)d_in[10];
    const float* bo    = (const float*)d_in[11];
    const float* ln2g  = (const float*)d_in[12];
    const float* ln2b  = (const float*)d_in[13];
    const float* w1    = (const float*)d_in[14];
    const float* b1    = (const float*)d_in[15];
    const float* w2    = (const float*)d_in[16];
    const float* b2    = (const float*)d_in[17];
    const float* flng  = (const float*)d_in[18];
    const float* flnb  = (const float*)d_in[19];

    float* h = (float*)d_out;                       // residual stream
    __bf16* y    = (__bf16*)d_ws;                   // [MR,768]
    __bf16* qkv  = y   + (size_t)MR * Hc;           // [MR,2304]
    __bf16* ob   = qkv + (size_t)MR * QS;           // [MR,768]
    __bf16* fb   = ob  + (size_t)MR * Hc;           // [MR,3072] FFN act
    __bf16* w1t  = fb  + (size_t)MR * FFc;          // [3072,768]
    __bf16* w2t  = w1t + (size_t)FFc * Hc;          // [768,3072]
    float*  bqkv = (float*)(w2t + (size_t)Hc * FFc);// [2304]
    // alias (dead before FFN act is written): QKV + O weights inside fb region
    __bf16* wqkvt = fb;                             // [2304,768]
    __bf16* wot   = fb + (size_t)QS * Hc;           // [768,768]

    hipMemcpyAsync(h, x, (size_t)MR * Hc * sizeof(float), hipMemcpyDeviceToDevice, stream);

    dim3 blk(256);
    dim3 gLN(MR / 4);
    dim3 gQKV(QS / 128, MR / 128);   // (18,64)
    dim3 gP64(Hc / 64, MR / 128);    // (12,64) = 768 blocks, 3/CU, 4 waves each
    dim3 gF(FFc / 128, MR / 128);    // (24,64)
    dim3 gA(Bc * NHc, Sc / 64);      // (192,8)
    dim3 gPrep(6921);                // fused weight prep

    for (int l = 0; l < Lc; ++l) {
        const float* wq_l = wq + (size_t)l * Hc * Hc;
        const float* wk_l = wk + (size_t)l * Hc * Hc;
        const float* wv_l = wv + (size_t)l * Hc * Hc;
        const float* wo_l = wo + (size_t)l * Hc * Hc;
        const float* w1_l = w1 + (size_t)l * Hc * FFc;
        const float* w2_l = w2 + (size_t)l * FFc * Hc;

        prep_k<<<gPrep, blk, 0, stream>>>(wq_l, wk_l, wv_l, wo_l, w1_l, w2_l,
                                          bq + l * Hc, bk + l * Hc, bv + l * Hc,
                                          wqkvt, wot, w1t, w2t, bqkv);

        ln_k<false><<<gLN, blk, 0, stream>>>(h, ln1g + l * Hc, ln1b + l * Hc, y, nullptr);
        gemm2_k<0, false><<<gQKV, blk, 0, stream>>>(y, wqkvt, bqkv, nullptr, nullptr, qkv, MR, QS, Hc);
        attn_k<<<gA, blk, 0, stream>>>(qkv, qkv + Hc, qkv + 2 * Hc, abias, ob);
        gemm3_k<<<gP64, blk, 0, stream>>>(ob, wot, bo + l * Hc, h, h, MR, Hc, Hc);
        ln_k<false><<<gLN, blk, 0, stream>>>(h, ln2g + l * Hc, ln2b + l * Hc, y, nullptr);
        gemm2_k<1, false><<<gF, blk, 0, stream>>>(y, w1t, b1 + l * FFc, nullptr, nullptr, fb, MR, FFc, Hc);
        gemm3_k<<<gP64, blk, 0, stream>>>(fb, w2t, b2 + l * Hc, h, h, MR, Hc, FFc);
    }
    ln_k<true><<<gLN, blk, 0, stream>>>(h, flng, flnb, nullptr, h);
}

// Round 3
// 1625.232 us; speedup vs baseline: 1.0797x; 1.0797x over previous
//
#include <hip/hip_runtime.h>
#include <math.h>

// ---------------- problem constants ----------------
constexpr int Lc = 4, Bc = 16, Sc = 512, Hc = 768, NHc = 12, FFc = 3072, Dc = 64;
constexpr int MR = Bc * Sc;            // 8192 token rows
constexpr int QS = 2304;               // fused QKV row stride
constexpr float SCALEc = 0.125f;       // D^-0.5

typedef __attribute__((ext_vector_type(8))) __bf16 bf16x8;
typedef __attribute__((ext_vector_type(4))) __bf16 bf16x4;
typedef __attribute__((ext_vector_type(4))) float  floatx4;

__device__ inline floatx4 mfma16(bf16x8 a, bf16x8 b, floatx4 c) {
    return __builtin_amdgcn_mfma_f32_16x16x32_bf16(a, b, c, 0, 0, 0);
}
__device__ inline float gelu_f(float x) {
    return 0.5f * x * (1.0f + erff(x * 0.70710678118654752f));
}
// async global->LDS, 16B per lane; LDS dest = wave-uniform base + lane*16
__device__ inline void ld16(const __bf16* g, __bf16* l) {
    __builtin_amdgcn_global_load_lds(
        (const __attribute__((address_space(1))) void*)g,
        (__attribute__((address_space(3))) void*)l, 16, 0, 0);
}

// ---------------- LayerNorm: one wave per row ----------
template<bool FINAL>
__global__ __launch_bounds__(256) void ln_k(
    const float* __restrict__ x, const float* __restrict__ g, const float* __restrict__ bt,
    __bf16* __restrict__ yb, float* __restrict__ yf)
{
    const int row  = blockIdx.x * 4 + (threadIdx.x >> 6);
    const int lane = threadIdx.x & 63;
    const int col  = lane * 12;
    const float* xr = x + (size_t)row * Hc + col;
    float v[12];
    *(float4*)(v + 0) = *(const float4*)(xr + 0);
    *(float4*)(v + 4) = *(const float4*)(xr + 4);
    *(float4*)(v + 8) = *(const float4*)(xr + 8);
    float s = 0.f, s2 = 0.f;
#pragma unroll
    for (int j = 0; j < 12; ++j) { s += v[j]; s2 += v[j] * v[j]; }
#pragma unroll
    for (int o = 32; o > 0; o >>= 1) { s += __shfl_xor(s, o); s2 += __shfl_xor(s2, o); }
    const float mean = s * (1.0f / Hc);
    const float inv  = rsqrtf(s2 * (1.0f / Hc) - mean * mean + 1e-5f);
    float gv[12], bv[12];
    *(float4*)(gv + 0) = *(const float4*)(g + col);
    *(float4*)(gv + 4) = *(const float4*)(g + col + 4);
    *(float4*)(gv + 8) = *(const float4*)(g + col + 8);
    *(float4*)(bv + 0) = *(const float4*)(bt + col);
    *(float4*)(bv + 4) = *(const float4*)(bt + col + 4);
    *(float4*)(bv + 8) = *(const float4*)(bt + col + 8);
    if (FINAL) {
        float o[12];
#pragma unroll
        for (int j = 0; j < 12; ++j) o[j] = (v[j] - mean) * inv * gv[j] + bv[j];
        float* yr = yf + (size_t)row * Hc + col;
        *(float4*)(yr + 0) = *(float4*)(o + 0);
        *(float4*)(yr + 4) = *(float4*)(o + 4);
        *(float4*)(yr + 8) = *(float4*)(o + 8);
    } else {
        __bf16 o[12];
#pragma unroll
        for (int j = 0; j < 12; ++j) o[j] = (__bf16)((v[j] - mean) * inv * gv[j] + bv[j]);
        __bf16* yr = yb + (size_t)row * Hc + col;
        *(bf16x4*)(yr + 0) = *(bf16x4*)(o + 0);
        *(bf16x4*)(yr + 4) = *(bf16x4*)(o + 4);
        *(bf16x4*)(yr + 8) = *(bf16x4*)(o + 8);
    }
}

// ---------------- unified per-layer weight prep ----------------
__global__ __launch_bounds__(256) void prep_k(
    const float* __restrict__ wq, const float* __restrict__ wk,
    const float* __restrict__ wv, const float* __restrict__ wo,
    const float* __restrict__ w1, const float* __restrict__ w2,
    const float* __restrict__ bq, const float* __restrict__ bk, const float* __restrict__ bv,
    __bf16* __restrict__ wqkvt, __bf16* __restrict__ wot,
    __bf16* __restrict__ w1t, __bf16* __restrict__ w2t, float* __restrict__ bqkv)
{
    const int id = blockIdx.x;
    if (id >= 6912) {                      // bias concat
        int i = (id - 6912) * 256 + threadIdx.x;
        if (i < QS) bqkv[i] = i < Hc ? bq[i] : (i < 2 * Hc ? bk[i - Hc] : bv[i - 2 * Hc]);
        return;
    }
    const float* in; __bf16* out; int R, C, tile;
    if (id < 2304) {
        int piece = id / 576; tile = id % 576; R = Hc; C = Hc;
        in  = piece == 0 ? wq : piece == 1 ? wk : piece == 2 ? wv : wo;
        out = piece == 3 ? wot : wqkvt + (size_t)piece * Hc * Hc;
    } else if (id < 4608) {
        tile = id - 2304; R = Hc; C = FFc; in = w1; out = w1t;
    } else {
        tile = id - 4608; R = FFc; C = Hc; in = w2; out = w2t;
    }
    const int nx = C / 32;
    const int bx = tile % nx, by = tile / nx;
    __shared__ float t[32][33];
    const int c0 = bx * 32, r0 = by * 32;
    const int tx = threadIdx.x & 31, ty = threadIdx.x >> 5;   // 32 x 8
#pragma unroll
    for (int i2 = 0; i2 < 4; ++i2)
        t[ty + i2 * 8][tx] = in[(size_t)(r0 + ty + i2 * 8) * C + c0 + tx];
    __syncthreads();
#pragma unroll
    for (int i2 = 0; i2 < 4; ++i2)
        out[(size_t)(c0 + ty + i2 * 8) * R + r0 + tx] = (__bf16)t[tx][ty + i2 * 8];
}

// ---------------- GEMM 128x128 (4 waves): for wide-N gemms (QKV, FFN1) --------
template<int ACT, bool RESID>
__global__ __launch_bounds__(256) void gemm2_k(
    const __bf16* __restrict__ A, const __bf16* __restrict__ Bt,
    const float* __restrict__ bias, const float* __restrict__ resid,
    float* __restrict__ outF, __bf16* __restrict__ outB,
    int M, int N, int K)
{
    __shared__ alignas(16) __bf16 As[128 * 32];
    __shared__ alignas(16) __bf16 Bs[128 * 32];
    const int tid  = threadIdx.x;
    const int wave = tid >> 6, lane = tid & 63, lhi = lane >> 4, llo = lane & 15;
    const int wm = wave >> 1, wn = wave & 1;
    const int row0 = blockIdx.y * 128, col0 = blockIdx.x * 128;
    const int srow = lane >> 2;            // 0..15
    const int scol = (lane & 3) * 8;       // 0,8,16,24

    floatx4 acc[4][4];
#pragma unroll
    for (int i = 0; i < 4; ++i)
#pragma unroll
        for (int j = 0; j < 4; ++j) acc[i][j] = {0.f, 0.f, 0.f, 0.f};

    const __bf16* Ab = A  + (size_t)(row0 + wave * 16 + srow) * K + scol;
    const __bf16* Bb = Bt + (size_t)(col0 + wave * 16 + srow) * K + scol;

    for (int kt = 0; kt < K; kt += 32) {
#pragma unroll
        for (int t = 0; t < 2; ++t) {
            ld16(Ab + (size_t)(t * 64) * K + kt, As + (t * 64 + wave * 16) * 32);
            ld16(Bb + (size_t)(t * 64) * K + kt, Bs + (t * 64 + wave * 16) * 32);
        }
        __syncthreads();
        bf16x8 af[4], bfr[4];
#pragma unroll
        for (int i = 0; i < 4; ++i)
            af[i]  = *(const bf16x8*)(As + (wm * 64 + i * 16 + llo) * 32 + lhi * 8);
#pragma unroll
        for (int j = 0; j < 4; ++j)
            bfr[j] = *(const bf16x8*)(Bs + (wn * 64 + j * 16 + llo) * 32 + lhi * 8);
#pragma unroll
        for (int i = 0; i < 4; ++i)
#pragma unroll
            for (int j = 0; j < 4; ++j)
                acc[i][j] = mfma16(af[i], bfr[j], acc[i][j]);
        __syncthreads();
    }
#pragma unroll
    for (int i = 0; i < 4; ++i) {
#pragma unroll
        for (int j = 0; j < 4; ++j) {
            int colc = col0 + wn * 64 + j * 16 + llo;
            float bb = bias[colc];
#pragma unroll
            for (int r = 0; r < 4; ++r) {
                int rowc = row0 + wm * 64 + i * 16 + lhi * 4 + r;
                float vv = acc[i][j][r] + bb;
                if (ACT == 1) vv = gelu_f(vv);
                size_t idx = (size_t)rowc * N + colc;
                if (RESID) outF[idx] = resid[idx] + vv;
                else       outB[idx] = (__bf16)vv;
            }
        }
    }
}

// ---------------- GEMM 128x64 pipelined (4 waves): N=768 resid gemms ----------
// v3: the round-2 counters showed gemm3 = 57% of runtime, MfmaUtil 12.5%,
// ~2830 cyc/K-step vs ~390 cyc of MFMA -> exposed load latency (stage was
// issued AFTER the barrier and drained immediately). Fix = T3 minimum
// 2-phase: double-buffered LDS, STAGE(t+1) issued BEFORE compute(t), ONE
// barrier per K-step. The pre-barrier vmcnt(0) now waits on loads that had
// the whole ds_read+MFMA phase to fly. 4 waves/block (each 32 rows x 64
// cols), 768 blocks -> 3 blocks/CU = 12 waves/CU. LDS 2x12 KB = 24 KB.
// All LDS patterns are contiguous-1024B-per-wave (conflict-free).
__global__ __launch_bounds__(256) void gemm3_k(
    const __bf16* __restrict__ A, const __bf16* __restrict__ Bt,
    const float* __restrict__ bias, const float* __restrict__ resid,
    float* __restrict__ outF, int M, int N, int K)
{
    __shared__ alignas(16) __bf16 As[2][128 * 32];
    __shared__ alignas(16) __bf16 Bs[2][64 * 32];
    const int tid  = threadIdx.x;
    const int wave = tid >> 6, lane = tid & 63, lhi = lane >> 4, llo = lane & 15;
    const int row0 = blockIdx.y * 128, col0 = blockIdx.x * 64;
    const int srow = lane >> 2;            // 0..15
    const int scol = (lane & 3) * 8;       // 0,8,16,24

    floatx4 acc[2][4];
#pragma unroll
    for (int i = 0; i < 2; ++i)
#pragma unroll
        for (int j = 0; j < 4; ++j) acc[i][j] = {0.f, 0.f, 0.f, 0.f};

    // wave w stages+computes A rows [w*32, w*32+32), all of Bs cols via rows [w*16,+16)
    const __bf16* Ab = A  + (size_t)(row0 + wave * 32 + srow) * K + scol;
    const __bf16* Bb = Bt + (size_t)(col0 + wave * 16 + srow) * K + scol;

    // stage K-tile at offset kt into buffer buf (3 x ld16 per thread)
#define G3_STAGE(buf, kt)                                                      \
    do {                                                                       \
        ld16(Ab + (kt),                   &As[buf][(wave * 32 +  0) * 32]);    \
        ld16(Ab + (size_t)16 * K + (kt),  &As[buf][(wave * 32 + 16) * 32]);    \
        ld16(Bb + (kt),                   &Bs[buf][(wave * 16) * 32]);         \
    } while (0)

    G3_STAGE(0, 0);
    __syncthreads();
    const int nt = K >> 5;
    for (int t = 0; t < nt; ++t) {
        const int cur = t & 1;
        if (t + 1 < nt) G3_STAGE(cur ^ 1, (size_t)(t + 1) * 32);
        bf16x8 af[2], bfr[4];
#pragma unroll
        for (int i = 0; i < 2; ++i)
            af[i]  = *(const bf16x8*)(&As[cur][(wave * 32 + i * 16 + llo) * 32 + lhi * 8]);
#pragma unroll
        for (int j = 0; j < 4; ++j)
            bfr[j] = *(const bf16x8*)(&Bs[cur][(j * 16 + llo) * 32 + lhi * 8]);
#pragma unroll
        for (int i = 0; i < 2; ++i)
#pragma unroll
            for (int j = 0; j < 4; ++j)
                acc[i][j] = mfma16(af[i], bfr[j], acc[i][j]);
        __syncthreads();
    }
#undef G3_STAGE

#pragma unroll
    for (int i = 0; i < 2; ++i) {
#pragma unroll
        for (int j = 0; j < 4; ++j) {
            int colc = col0 + j * 16 + llo;
            float bb = bias[colc];
#pragma unroll
            for (int r = 0; r < 4; ++r) {
                int rowc = row0 + wave * 32 + i * 16 + lhi * 4 + r;
                size_t idx = (size_t)rowc * N + colc;
                outF[idx] = resid[idx] + acc[i][j][r] + bb;
            }
        }
    }
}

// ---------------- Flash attention (v2) ----------------
__global__ __launch_bounds__(256) void attn_k(
    const __bf16* __restrict__ q, const __bf16* __restrict__ k,
    const __bf16* __restrict__ v, const float* __restrict__ bias,
    __bf16* __restrict__ o)
{
    __shared__ alignas(16) __bf16 QPs[64][72];     // Q staging, then P tiles
    __shared__ alignas(16) __bf16 Ks[2][64][72];
    __shared__ alignas(16) __bf16 Vt[2][64][66];   // [d][t], stride 66

    const int hh = blockIdx.x % NHc, b = blockIdx.x / NHc, qt = blockIdx.y;
    const int tid = threadIdx.x, wave = tid >> 6, lane = tid & 63;
    const int lhi = lane >> 4, llo = lane & 15;
    const size_t base  = (size_t)b * Sc * QS + hh * Dc;   // qkv addressing
    const size_t obase = (size_t)b * Sc * Hc + hh * Dc;   // output addressing

    const int sr0 = tid >> 3;          // 0..31 (and +32 for 2nd chunk)
    const int sc0 = (tid & 7) * 8;     // 0..56

    // ---- prologue: stage Q and tile-0 K/V
    {
        bf16x8 q0 = *(const bf16x8*)(q + base + (size_t)(qt * 64 + sr0) * QS + sc0);
        bf16x8 q1 = *(const bf16x8*)(q + base + (size_t)(qt * 64 + sr0 + 32) * QS + sc0);
        *(bf16x8*)(&QPs[sr0][sc0])      = q0;
        *(bf16x8*)(&QPs[sr0 + 32][sc0]) = q1;
        bf16x8 k0 = *(const bf16x8*)(k + base + (size_t)(sr0) * QS + sc0);
        bf16x8 k1 = *(const bf16x8*)(k + base + (size_t)(sr0 + 32) * QS + sc0);
        *(bf16x8*)(&Ks[0][sr0][sc0])      = k0;
        *(bf16x8*)(&Ks[0][sr0 + 32][sc0]) = k1;
        bf16x8 v0 = *(const bf16x8*)(v + base + (size_t)(sr0) * QS + sc0);
        bf16x8 v1 = *(const bf16x8*)(v + base + (size_t)(sr0 + 32) * QS + sc0);
#pragma unroll
        for (int jj = 0; jj < 8; ++jj) {
            Vt[0][sc0 + jj][sr0]      = v0[jj];
            Vt[0][sc0 + jj][sr0 + 32] = v1[jj];
        }
    }
    __syncthreads();

    // Q fragments -> registers (QPs becomes free for Ps reuse; wave-local)
    bf16x8 aq0 = *(const bf16x8*)(&QPs[wave * 16 + llo][0 * 32 + lhi * 8]);
    bf16x8 aq1 = *(const bf16x8*)(&QPs[wave * 16 + llo][1 * 32 + lhi * 8]);

    float m_reg[4], l_reg[4];
#pragma unroll
    for (int r = 0; r < 4; ++r) { m_reg[r] = -1e30f; l_reg[r] = 0.f; }

    floatx4 acco[4];
#pragma unroll
    for (int j = 0; j < 4; ++j) acco[j] = {0.f, 0.f, 0.f, 0.f};

    const float* brow = bias + ((size_t)(b * NHc + hh) * Sc + qt * 64) * Sc;

    // bias prefetch for tile 0
    float bnx[4][4];
#pragma unroll
    for (int nf = 0; nf < 4; ++nf)
#pragma unroll
        for (int r = 0; r < 4; ++r)
            bnx[nf][r] = brow[(size_t)(wave * 16 + lhi * 4 + r) * Sc + nf * 16 + llo];

    for (int it = 0; it < 8; ++it) {
        const int cur = it & 1;
        // 1) issue next-tile K/V global loads (consumed at step 6)
        bf16x8 k0, k1, v0, v1;
        if (it < 7) {
            const int ktn = (it + 1) * 64;
            k0 = *(const bf16x8*)(k + base + (size_t)(ktn + sr0) * QS + sc0);
            k1 = *(const bf16x8*)(k + base + (size_t)(ktn + sr0 + 32) * QS + sc0);
            v0 = *(const bf16x8*)(v + base + (size_t)(ktn + sr0) * QS + sc0);
            v1 = *(const bf16x8*)(v + base + (size_t)(ktn + sr0 + 32) * QS + sc0);
        }
        // 2) QK^T on buffer cur
        floatx4 accs[4];
#pragma unroll
        for (int j = 0; j < 4; ++j) accs[j] = {0.f, 0.f, 0.f, 0.f};
#pragma unroll
        for (int nf = 0; nf < 4; ++nf) {
            bf16x8 bk2 = *(const bf16x8*)(&Ks[cur][nf * 16 + llo][lhi * 8]);
            accs[nf] = mfma16(aq0, bk2, accs[nf]);
        }
#pragma unroll
        for (int nf = 0; nf < 4; ++nf) {
            bf16x8 bk2 = *(const bf16x8*)(&Ks[cur][nf * 16 + llo][32 + lhi * 8]);
            accs[nf] = mfma16(aq1, bk2, accs[nf]);
        }
        // 3) scores = acc*scale + bias (consumes bnx for THIS tile)
        float sv[4][4];
#pragma unroll
        for (int nf = 0; nf < 4; ++nf)
#pragma unroll
            for (int r = 0; r < 4; ++r)
                sv[nf][r] = accs[nf][r] * SCALEc + bnx[nf][r];
        // 4) prefetch bias for next tile (registers now free)
        if (it < 7) {
            const int ktn = (it + 1) * 64;
#pragma unroll
            for (int nf = 0; nf < 4; ++nf)
#pragma unroll
                for (int r = 0; r < 4; ++r)
                    bnx[nf][r] = brow[(size_t)(wave * 16 + lhi * 4 + r) * Sc + ktn + nf * 16 + llo];
        }
        // 5) in-register online softmax (rows live in 16-lane llo groups)
        float al[4];
#pragma unroll
        for (int r = 0; r < 4; ++r) {
            float mx = fmaxf(fmaxf(sv[0][r], sv[1][r]), fmaxf(sv[2][r], sv[3][r]));
            mx = fmaxf(mx, __shfl_xor(mx, 1));
            mx = fmaxf(mx, __shfl_xor(mx, 2));
            mx = fmaxf(mx, __shfl_xor(mx, 4));
            mx = fmaxf(mx, __shfl_xor(mx, 8));
            float mnew = fmaxf(m_reg[r], mx);
            al[r] = __expf(m_reg[r] - mnew);
            m_reg[r] = mnew;
            float sum = 0.f;
#pragma unroll
            for (int nf = 0; nf < 4; ++nf) {
                float p = __expf(sv[nf][r] - mnew);
                sum += p;
                QPs[wave * 16 + lhi * 4 + r][nf * 16 + llo] = (__bf16)p;  // wave-local
            }
            sum += __shfl_xor(sum, 1);
            sum += __shfl_xor(sum, 2);
            sum += __shfl_xor(sum, 4);
            sum += __shfl_xor(sum, 8);
            l_reg[r] = l_reg[r] * al[r] + sum;
        }
        // rescale running O
#pragma unroll
        for (int nf = 0; nf < 4; ++nf)
#pragma unroll
            for (int r = 0; r < 4; ++r) acco[nf][r] *= al[r];
        // PV on buffer cur (Ps wave-local: in-order DS per wave, no barrier)
#pragma unroll
        for (int kk = 0; kk < 2; ++kk) {
            bf16x8 ap = *(const bf16x8*)(&QPs[wave * 16 + llo][kk * 32 + lhi * 8]);
#pragma unroll
            for (int nf = 0; nf < 4; ++nf) {
                bf16x8 bv2 = *(const bf16x8*)(&Vt[cur][nf * 16 + llo][kk * 32 + lhi * 8]);
                acco[nf] = mfma16(ap, bv2, acco[nf]);
            }
        }
        // 6) write next-tile K/V into buffer cur^1
        if (it < 7) {
            *(bf16x8*)(&Ks[cur ^ 1][sr0][sc0])      = k0;
            *(bf16x8*)(&Ks[cur ^ 1][sr0 + 32][sc0]) = k1;
#pragma unroll
            for (int jj = 0; jj < 8; ++jj) {
                Vt[cur ^ 1][sc0 + jj][sr0]      = v0[jj];
                Vt[cur ^ 1][sc0 + jj][sr0 + 32] = v1[jj];
            }
        }
        // 7) single barrier per tile
        __syncthreads();
    }
#pragma unroll
    for (int nf = 0; nf < 4; ++nf) {
#pragma unroll
        for (int r = 0; r < 4; ++r) {
            int lr = wave * 16 + lhi * 4 + r;
            float oo = acco[nf][r] / l_reg[r];
            o[obase + (size_t)(qt * 64 + lr) * Hc + nf * 16 + llo] = (__bf16)oo;
        }
    }
}

// ---------------- orchestration ----------------
extern "C" void kernel_launch(void* const* d_in, const int* in_sizes, int n_in,
                              void* d_out, int out_size, void* d_ws, size_t ws_size,
                              hipStream_t stream)
{
    const float* x     = (const float*)d_in[0];
    const float* abias = (const float*)d_in[1];
    const float* ln1g  = (const float*)d_in[2];
    const float* ln1b  = (const float*)d_in[3];
    const float* wq    = (const float*)d_in[4];
    const float* bq    = (const float*)d_in[5];
    const float* wk    = (const float*)d_in[6];
    const float* bk    = (const float*)d_in[7];
    const float* wv    = (const float*)d_in[8];
    const float* bv    = (const float*)d_in[9];
    const float* wo    = (const float*)d_in[10];
    const float* bo    = (const float*)d_in[11];
    const float* ln2g  = (const float*)d_in[12];
    const float* ln2b  = (const float*)d_in[13];
    const float* w1    = (const float*)d_in[14];
    const float* b1    = (const float*)d_in[15];
    const float* w2    = (const float*)d_in[16];
    const float* b2    = (const float*)d_in[17];
    const float* flng  = (const float*)d_in[18];
    const float* flnb  = (const float*)d_in[19];

    float* h = (float*)d_out;                       // residual stream
    __bf16* y    = (__bf16*)d_ws;                   // [MR,768]
    __bf16* qkv  = y   + (size_t)MR * Hc;           // [MR,2304]
    __bf16* ob   = qkv + (size_t)MR * QS;           // [MR,768]
    __bf16* fb   = ob  + (size_t)MR * Hc;           // [MR,3072] FFN act
    __bf16* w1t  = fb  + (size_t)MR * FFc;          // [3072,768]
    __bf16* w2t  = w1t + (size_t)FFc * Hc;          // [768,3072]
    float*  bqkv = (float*)(w2t + (size_t)Hc * FFc);// [2304]
    // alias (dead before FFN act is written): QKV + O weights inside fb region
    __bf16* wqkvt = fb;                             // [2304,768]
    __bf16* wot   = fb + (size_t)QS * Hc;           // [768,768]

    hipMemcpyAsync(h, x, (size_t)MR * Hc * sizeof(float), hipMemcpyDeviceToDevice, stream);

    dim3 blk(256);
    dim3 gLN(MR / 4);
    dim3 gQKV(QS / 128, MR / 128);   // (18,64)
    dim3 gP64(Hc / 64, MR / 128);    // (12,64) = 768 blocks, 3/CU, 4 waves each
    dim3 gF(FFc / 128, MR / 128);    // (24,64)
    dim3 gA(Bc * NHc, Sc / 64);      // (192,8)
    dim3 gPrep(6921);                // fused weight prep

    for (int l = 0; l < Lc; ++l) {
        const float* wq_l = wq + (size_t)l * Hc * Hc;
        const float* wk_l = wk + (size_t)l * Hc * Hc;
        const float* wv_l = wv + (size_t)l * Hc * Hc;
        const float* wo_l = wo + (size_t)l * Hc * Hc;
        const float* w1_l = w1 + (size_t)l * Hc * FFc;
        const float* w2_l = w2 + (size_t)l * FFc * Hc;

        prep_k<<<gPrep, blk, 0, stream>>>(wq_l, wk_l, wv_l, wo_l, w1_l, w2_l,
                                          bq + l * Hc, bk + l * Hc, bv + l * Hc,
                                          wqkvt, wot, w1t, w2t, bqkv);

        ln_k<false><<<gLN, blk, 0, stream>>>(h, ln1g + l * Hc, ln1b + l * Hc, y, nullptr);
        gemm2_k<0, false><<<gQKV, blk, 0, stream>>>(y, wqkvt, bqkv, nullptr, nullptr, qkv, MR, QS, Hc);
        attn_k<<<gA, blk, 0, stream>>>(qkv, qkv + Hc, qkv + 2 * Hc, abias, ob);
        gemm3_k<<<gP64, blk, 0, stream>>>(ob, wot, bo + l * Hc, h, h, MR, Hc, Hc);
        ln_k<false><<<gLN, blk, 0, stream>>>(h, ln2g + l * Hc, ln2b + l * Hc, y, nullptr);
        gemm2_k<1, false><<<gF, blk, 0, stream>>>(y, w1t, b1 + l * FFc, nullptr, nullptr, fb, MR, FFc, Hc);
        gemm3_k<<<gP64, blk, 0, stream>>>(fb, w2t, b2 + l * Hc, h, h, MR, Hc, FFc);
    }
    ln_k<true><<<gLN, blk, 0, stream>>>(h, flng, flnb, nullptr, h);
}

// Round 4
// 1543.067 us; speedup vs baseline: 1.1372x; 1.0532x over previous
//
#include <hip/hip_runtime.h>
#include <math.h>

// ---------------- problem constants ----------------
constexpr int Lc = 4, Bc = 16, Sc = 512, Hc = 768, NHc = 12, FFc = 3072, Dc = 64;
constexpr int MR = Bc * Sc;            // 8192 token rows
constexpr int QS = 2304;               // fused QKV row stride
constexpr float SCALEc = 0.125f;       // D^-0.5

typedef __attribute__((ext_vector_type(8))) __bf16 bf16x8;
typedef __attribute__((ext_vector_type(4))) __bf16 bf16x4;
typedef __attribute__((ext_vector_type(4))) float  floatx4;

__device__ inline floatx4 mfma16(bf16x8 a, bf16x8 b, floatx4 c) {
    return __builtin_amdgcn_mfma_f32_16x16x32_bf16(a, b, c, 0, 0, 0);
}
__device__ inline float gelu_f(float x) {
    return 0.5f * x * (1.0f + erff(x * 0.70710678118654752f));
}
// async global->LDS, 16B per lane; LDS dest = wave-uniform base + lane*16
__device__ inline void ld16(const __bf16* g, __bf16* l) {
    __builtin_amdgcn_global_load_lds(
        (const __attribute__((address_space(1))) void*)g,
        (__attribute__((address_space(3))) void*)l, 16, 0, 0);
}

// counted waits (T4): loads for tile t+1 stay in flight across the barrier
#define WAITVM4   asm volatile("s_waitcnt vmcnt(4)" ::: "memory")
#define WAITVM3   asm volatile("s_waitcnt vmcnt(3)" ::: "memory")
#define WAITVM0   asm volatile("s_waitcnt vmcnt(0)" ::: "memory")
#define WAITLGKM0 asm volatile("s_waitcnt lgkmcnt(0)" ::: "memory")
#define SBAR      __builtin_amdgcn_s_barrier()

// ---------------- LayerNorm: one wave per row ----------
template<bool FINAL>
__global__ __launch_bounds__(256) void ln_k(
    const float* __restrict__ x, const float* __restrict__ g, const float* __restrict__ bt,
    __bf16* __restrict__ yb, float* __restrict__ yf)
{
    const int row  = blockIdx.x * 4 + (threadIdx.x >> 6);
    const int lane = threadIdx.x & 63;
    const int col  = lane * 12;
    const float* xr = x + (size_t)row * Hc + col;
    float v[12];
    *(float4*)(v + 0) = *(const float4*)(xr + 0);
    *(float4*)(v + 4) = *(const float4*)(xr + 4);
    *(float4*)(v + 8) = *(const float4*)(xr + 8);
    float s = 0.f, s2 = 0.f;
#pragma unroll
    for (int j = 0; j < 12; ++j) { s += v[j]; s2 += v[j] * v[j]; }
#pragma unroll
    for (int o = 32; o > 0; o >>= 1) { s += __shfl_xor(s, o); s2 += __shfl_xor(s2, o); }
    const float mean = s * (1.0f / Hc);
    const float inv  = rsqrtf(s2 * (1.0f / Hc) - mean * mean + 1e-5f);
    float gv[12], bv[12];
    *(float4*)(gv + 0) = *(const float4*)(g + col);
    *(float4*)(gv + 4) = *(const float4*)(g + col + 4);
    *(float4*)(gv + 8) = *(const float4*)(g + col + 8);
    *(float4*)(bv + 0) = *(const float4*)(bt + col);
    *(float4*)(bv + 4) = *(const float4*)(bt + col + 4);
    *(float4*)(bv + 8) = *(const float4*)(bt + col + 8);
    if (FINAL) {
        float o[12];
#pragma unroll
        for (int j = 0; j < 12; ++j) o[j] = (v[j] - mean) * inv * gv[j] + bv[j];
        float* yr = yf + (size_t)row * Hc + col;
        *(float4*)(yr + 0) = *(float4*)(o + 0);
        *(float4*)(yr + 4) = *(float4*)(o + 4);
        *(float4*)(yr + 8) = *(float4*)(o + 8);
    } else {
        __bf16 o[12];
#pragma unroll
        for (int j = 0; j < 12; ++j) o[j] = (__bf16)((v[j] - mean) * inv * gv[j] + bv[j]);
        __bf16* yr = yb + (size_t)row * Hc + col;
        *(bf16x4*)(yr + 0) = *(bf16x4*)(o + 0);
        *(bf16x4*)(yr + 4) = *(bf16x4*)(o + 4);
        *(bf16x4*)(yr + 8) = *(bf16x4*)(o + 8);
    }
}

// ---------------- unified per-layer weight prep ----------------
__global__ __launch_bounds__(256) void prep_k(
    const float* __restrict__ wq, const float* __restrict__ wk,
    const float* __restrict__ wv, const float* __restrict__ wo,
    const float* __restrict__ w1, const float* __restrict__ w2,
    const float* __restrict__ bq, const float* __restrict__ bk, const float* __restrict__ bv,
    __bf16* __restrict__ wqkvt, __bf16* __restrict__ wot,
    __bf16* __restrict__ w1t, __bf16* __restrict__ w2t, float* __restrict__ bqkv)
{
    const int id = blockIdx.x;
    if (id >= 6912) {                      // bias concat
        int i = (id - 6912) * 256 + threadIdx.x;
        if (i < QS) bqkv[i] = i < Hc ? bq[i] : (i < 2 * Hc ? bk[i - Hc] : bv[i - 2 * Hc]);
        return;
    }
    const float* in; __bf16* out; int R, C, tile;
    if (id < 2304) {
        int piece = id / 576; tile = id % 576; R = Hc; C = Hc;
        in  = piece == 0 ? wq : piece == 1 ? wk : piece == 2 ? wv : wo;
        out = piece == 3 ? wot : wqkvt + (size_t)piece * Hc * Hc;
    } else if (id < 4608) {
        tile = id - 2304; R = Hc; C = FFc; in = w1; out = w1t;
    } else {
        tile = id - 4608; R = FFc; C = Hc; in = w2; out = w2t;
    }
    const int nx = C / 32;
    const int bx = tile % nx, by = tile / nx;
    __shared__ float t[32][33];
    const int c0 = bx * 32, r0 = by * 32;
    const int tx = threadIdx.x & 31, ty = threadIdx.x >> 5;   // 32 x 8
#pragma unroll
    for (int i2 = 0; i2 < 4; ++i2)
        t[ty + i2 * 8][tx] = in[(size_t)(r0 + ty + i2 * 8) * C + c0 + tx];
    __syncthreads();
#pragma unroll
    for (int i2 = 0; i2 < 4; ++i2)
        out[(size_t)(c0 + ty + i2 * 8) * R + r0 + tx] = (__bf16)t[tx][ty + i2 * 8];
}

// ---------------- GEMM 128x128 (4 waves), dbuf + counted vmcnt + XCD swizzle --
// v2: double-buffered LDS (32 KB), STAGE(t+1) issued before compute(t), raw
// s_barrier with vmcnt(4) (never 0 mid-loop) so prefetch loads span the whole
// iteration. XCD swizzle groups 8 row-panels per XCD -> A-panel L2 reuse.
template<int ACT, bool RESID>
__global__ __launch_bounds__(256) void gemm2_k(
    const __bf16* __restrict__ A, const __bf16* __restrict__ Bt,
    const float* __restrict__ bias, const float* __restrict__ resid,
    float* __restrict__ outF, __bf16* __restrict__ outB,
    int M, int N, int K)
{
    __shared__ alignas(16) __bf16 As[2][128 * 32];
    __shared__ alignas(16) __bf16 Bs[2][128 * 32];
    const int tid  = threadIdx.x;
    const int wave = tid >> 6, lane = tid & 63, lhi = lane >> 4, llo = lane & 15;
    const int wm = wave >> 1, wn = wave & 1;

    // XCD-aware bijective swizzle (grid counts are %8==0)
    const int nxb = gridDim.x, nb = nxb * gridDim.y;
    const int bid = blockIdx.y * nxb + blockIdx.x;
    const int swz = (bid & 7) * (nb >> 3) + (bid >> 3);
    const int row0 = (swz / nxb) * 128, col0 = (swz % nxb) * 128;

    const int srow = lane >> 2;            // 0..15
    const int scol = (lane & 3) * 8;       // 0,8,16,24

    floatx4 acc[4][4];
#pragma unroll
    for (int i = 0; i < 4; ++i)
#pragma unroll
        for (int j = 0; j < 4; ++j) acc[i][j] = {0.f, 0.f, 0.f, 0.f};

    const __bf16* Ab = A  + (size_t)(row0 + wave * 16 + srow) * K + scol;
    const __bf16* Bb = Bt + (size_t)(col0 + wave * 16 + srow) * K + scol;

#define G2_STAGE(buf, kt)                                                      \
    do {                                                                       \
        ld16(Ab + (kt),                  &As[buf][(wave * 16) * 32]);          \
        ld16(Ab + (size_t)64 * K + (kt), &As[buf][(64 + wave * 16) * 32]);     \
        ld16(Bb + (kt),                  &Bs[buf][(wave * 16) * 32]);          \
        ld16(Bb + (size_t)64 * K + (kt), &Bs[buf][(64 + wave * 16) * 32]);     \
    } while (0)

    G2_STAGE(0, 0);
    const int nt = K >> 5;
    for (int t = 0; t < nt; ++t) {
        const int cur = t & 1;
        if (t + 1 < nt) { G2_STAGE(cur ^ 1, (size_t)(t + 1) * 32); WAITVM4; }
        else            { WAITVM0; }
        SBAR;
        __builtin_amdgcn_sched_barrier(0);
        bf16x8 af[4], bfr[4];
#pragma unroll
        for (int i = 0; i < 4; ++i)
            af[i]  = *(const bf16x8*)(&As[cur][(wm * 64 + i * 16 + llo) * 32 + lhi * 8]);
#pragma unroll
        for (int j = 0; j < 4; ++j)
            bfr[j] = *(const bf16x8*)(&Bs[cur][(wn * 64 + j * 16 + llo) * 32 + lhi * 8]);
#pragma unroll
        for (int i = 0; i < 4; ++i)
#pragma unroll
            for (int j = 0; j < 4; ++j)
                acc[i][j] = mfma16(af[i], bfr[j], acc[i][j]);
        WAITLGKM0;
        SBAR;
    }
#undef G2_STAGE

#pragma unroll
    for (int i = 0; i < 4; ++i) {
#pragma unroll
        for (int j = 0; j < 4; ++j) {
            int colc = col0 + wn * 64 + j * 16 + llo;
            float bb = bias[colc];
#pragma unroll
            for (int r = 0; r < 4; ++r) {
                int rowc = row0 + wm * 64 + i * 16 + lhi * 4 + r;
                float vv = acc[i][j][r] + bb;
                if (ACT == 1) vv = gelu_f(vv);
                size_t idx = (size_t)rowc * N + colc;
                if (RESID) outF[idx] = resid[idx] + vv;
                else       outB[idx] = (__bf16)vv;
            }
        }
    }
}

// ---------------- GEMM 128x64 (4 waves), dbuf + counted vmcnt + XCD swizzle ---
// v4: round-3 kept __syncthreads() -> vmcnt(0) drained the just-issued
// prefetch every K-step. Now raw barriers + vmcnt(3): stage(t+1) stays in
// flight across the barrier and has a full iteration to land.
__global__ __launch_bounds__(256) void gemm3_k(
    const __bf16* __restrict__ A, const __bf16* __restrict__ Bt,
    const float* __restrict__ bias, const float* __restrict__ resid,
    float* __restrict__ outF, int M, int N, int K)
{
    __shared__ alignas(16) __bf16 As[2][128 * 32];
    __shared__ alignas(16) __bf16 Bs[2][64 * 32];
    const int tid  = threadIdx.x;
    const int wave = tid >> 6, lane = tid & 63, lhi = lane >> 4, llo = lane & 15;

    const int nxb = gridDim.x, nb = nxb * gridDim.y;   // (12, 64) -> 768
    const int bid = blockIdx.y * nxb + blockIdx.x;
    const int swz = (bid & 7) * (nb >> 3) + (bid >> 3);
    const int row0 = (swz / nxb) * 128, col0 = (swz % nxb) * 64;

    const int srow = lane >> 2;            // 0..15
    const int scol = (lane & 3) * 8;       // 0,8,16,24

    floatx4 acc[2][4];
#pragma unroll
    for (int i = 0; i < 2; ++i)
#pragma unroll
        for (int j = 0; j < 4; ++j) acc[i][j] = {0.f, 0.f, 0.f, 0.f};

    // wave w stages+computes A rows [w*32, +32); stages Bs rows [w*16, +16)
    const __bf16* Ab = A  + (size_t)(row0 + wave * 32 + srow) * K + scol;
    const __bf16* Bb = Bt + (size_t)(col0 + wave * 16 + srow) * K + scol;

#define G3_STAGE(buf, kt)                                                      \
    do {                                                                       \
        ld16(Ab + (kt),                  &As[buf][(wave * 32 +  0) * 32]);     \
        ld16(Ab + (size_t)16 * K + (kt), &As[buf][(wave * 32 + 16) * 32]);     \
        ld16(Bb + (kt),                  &Bs[buf][(wave * 16) * 32]);          \
    } while (0)

    G3_STAGE(0, 0);
    const int nt = K >> 5;
    for (int t = 0; t < nt; ++t) {
        const int cur = t & 1;
        if (t + 1 < nt) { G3_STAGE(cur ^ 1, (size_t)(t + 1) * 32); WAITVM3; }
        else            { WAITVM0; }
        SBAR;
        __builtin_amdgcn_sched_barrier(0);
        bf16x8 af[2], bfr[4];
#pragma unroll
        for (int i = 0; i < 2; ++i)
            af[i]  = *(const bf16x8*)(&As[cur][(wave * 32 + i * 16 + llo) * 32 + lhi * 8]);
#pragma unroll
        for (int j = 0; j < 4; ++j)
            bfr[j] = *(const bf16x8*)(&Bs[cur][(j * 16 + llo) * 32 + lhi * 8]);
#pragma unroll
        for (int i = 0; i < 2; ++i)
#pragma unroll
            for (int j = 0; j < 4; ++j)
                acc[i][j] = mfma16(af[i], bfr[j], acc[i][j]);
        WAITLGKM0;
        SBAR;
    }
#undef G3_STAGE

#pragma unroll
    for (int i = 0; i < 2; ++i) {
#pragma unroll
        for (int j = 0; j < 4; ++j) {
            int colc = col0 + j * 16 + llo;
            float bb = bias[colc];
#pragma unroll
            for (int r = 0; r < 4; ++r) {
                int rowc = row0 + wave * 32 + i * 16 + lhi * 4 + r;
                size_t idx = (size_t)rowc * N + colc;
                outF[idx] = resid[idx] + acc[i][j][r] + bb;
            }
        }
    }
}

// ---------------- Flash attention (v2) ----------------
__global__ __launch_bounds__(256) void attn_k(
    const __bf16* __restrict__ q, const __bf16* __restrict__ k,
    const __bf16* __restrict__ v, const float* __restrict__ bias,
    __bf16* __restrict__ o)
{
    __shared__ alignas(16) __bf16 QPs[64][72];     // Q staging, then P tiles
    __shared__ alignas(16) __bf16 Ks[2][64][72];
    __shared__ alignas(16) __bf16 Vt[2][64][66];   // [d][t], stride 66

    const int hh = blockIdx.x % NHc, b = blockIdx.x / NHc, qt = blockIdx.y;
    const int tid = threadIdx.x, wave = tid >> 6, lane = tid & 63;
    const int lhi = lane >> 4, llo = lane & 15;
    const size_t base  = (size_t)b * Sc * QS + hh * Dc;   // qkv addressing
    const size_t obase = (size_t)b * Sc * Hc + hh * Dc;   // output addressing

    const int sr0 = tid >> 3;          // 0..31 (and +32 for 2nd chunk)
    const int sc0 = (tid & 7) * 8;     // 0..56

    // ---- prologue: stage Q and tile-0 K/V
    {
        bf16x8 q0 = *(const bf16x8*)(q + base + (size_t)(qt * 64 + sr0) * QS + sc0);
        bf16x8 q1 = *(const bf16x8*)(q + base + (size_t)(qt * 64 + sr0 + 32) * QS + sc0);
        *(bf16x8*)(&QPs[sr0][sc0])      = q0;
        *(bf16x8*)(&QPs[sr0 + 32][sc0]) = q1;
        bf16x8 k0 = *(const bf16x8*)(k + base + (size_t)(sr0) * QS + sc0);
        bf16x8 k1 = *(const bf16x8*)(k + base + (size_t)(sr0 + 32) * QS + sc0);
        *(bf16x8*)(&Ks[0][sr0][sc0])      = k0;
        *(bf16x8*)(&Ks[0][sr0 + 32][sc0]) = k1;
        bf16x8 v0 = *(const bf16x8*)(v + base + (size_t)(sr0) * QS + sc0);
        bf16x8 v1 = *(const bf16x8*)(v + base + (size_t)(sr0 + 32) * QS + sc0);
#pragma unroll
        for (int jj = 0; jj < 8; ++jj) {
            Vt[0][sc0 + jj][sr0]      = v0[jj];
            Vt[0][sc0 + jj][sr0 + 32] = v1[jj];
        }
    }
    __syncthreads();

    // Q fragments -> registers (QPs becomes free for Ps reuse; wave-local)
    bf16x8 aq0 = *(const bf16x8*)(&QPs[wave * 16 + llo][0 * 32 + lhi * 8]);
    bf16x8 aq1 = *(const bf16x8*)(&QPs[wave * 16 + llo][1 * 32 + lhi * 8]);

    float m_reg[4], l_reg[4];
#pragma unroll
    for (int r = 0; r < 4; ++r) { m_reg[r] = -1e30f; l_reg[r] = 0.f; }

    floatx4 acco[4];
#pragma unroll
    for (int j = 0; j < 4; ++j) acco[j] = {0.f, 0.f, 0.f, 0.f};

    const float* brow = bias + ((size_t)(b * NHc + hh) * Sc + qt * 64) * Sc;

    // bias prefetch for tile 0
    float bnx[4][4];
#pragma unroll
    for (int nf = 0; nf < 4; ++nf)
#pragma unroll
        for (int r = 0; r < 4; ++r)
            bnx[nf][r] = brow[(size_t)(wave * 16 + lhi * 4 + r) * Sc + nf * 16 + llo];

    for (int it = 0; it < 8; ++it) {
        const int cur = it & 1;
        // 1) issue next-tile K/V global loads (consumed at step 6)
        bf16x8 k0, k1, v0, v1;
        if (it < 7) {
            const int ktn = (it + 1) * 64;
            k0 = *(const bf16x8*)(k + base + (size_t)(ktn + sr0) * QS + sc0);
            k1 = *(const bf16x8*)(k + base + (size_t)(ktn + sr0 + 32) * QS + sc0);
            v0 = *(const bf16x8*)(v + base + (size_t)(ktn + sr0) * QS + sc0);
            v1 = *(const bf16x8*)(v + base + (size_t)(ktn + sr0 + 32) * QS + sc0);
        }
        // 2) QK^T on buffer cur
        floatx4 accs[4];
#pragma unroll
        for (int j = 0; j < 4; ++j) accs[j] = {0.f, 0.f, 0.f, 0.f};
#pragma unroll
        for (int nf = 0; nf < 4; ++nf) {
            bf16x8 bk2 = *(const bf16x8*)(&Ks[cur][nf * 16 + llo][lhi * 8]);
            accs[nf] = mfma16(aq0, bk2, accs[nf]);
        }
#pragma unroll
        for (int nf = 0; nf < 4; ++nf) {
            bf16x8 bk2 = *(const bf16x8*)(&Ks[cur][nf * 16 + llo][32 + lhi * 8]);
            accs[nf] = mfma16(aq1, bk2, accs[nf]);
        }
        // 3) scores = acc*scale + bias (consumes bnx for THIS tile)
        float sv[4][4];
#pragma unroll
        for (int nf = 0; nf < 4; ++nf)
#pragma unroll
            for (int r = 0; r < 4; ++r)
                sv[nf][r] = accs[nf][r] * SCALEc + bnx[nf][r];
        // 4) prefetch bias for next tile (registers now free)
        if (it < 7) {
            const int ktn = (it + 1) * 64;
#pragma unroll
            for (int nf = 0; nf < 4; ++nf)
#pragma unroll
                for (int r = 0; r < 4; ++r)
                    bnx[nf][r] = brow[(size_t)(wave * 16 + lhi * 4 + r) * Sc + ktn + nf * 16 + llo];
        }
        // 5) in-register online softmax (rows live in 16-lane llo groups)
        float al[4];
#pragma unroll
        for (int r = 0; r < 4; ++r) {
            float mx = fmaxf(fmaxf(sv[0][r], sv[1][r]), fmaxf(sv[2][r], sv[3][r]));
            mx = fmaxf(mx, __shfl_xor(mx, 1));
            mx = fmaxf(mx, __shfl_xor(mx, 2));
            mx = fmaxf(mx, __shfl_xor(mx, 4));
            mx = fmaxf(mx, __shfl_xor(mx, 8));
            float mnew = fmaxf(m_reg[r], mx);
            al[r] = __expf(m_reg[r] - mnew);
            m_reg[r] = mnew;
            float sum = 0.f;
#pragma unroll
            for (int nf = 0; nf < 4; ++nf) {
                float p = __expf(sv[nf][r] - mnew);
                sum += p;
                QPs[wave * 16 + lhi * 4 + r][nf * 16 + llo] = (__bf16)p;  // wave-local
            }
            sum += __shfl_xor(sum, 1);
            sum += __shfl_xor(sum, 2);
            sum += __shfl_xor(sum, 4);
            sum += __shfl_xor(sum, 8);
            l_reg[r] = l_reg[r] * al[r] + sum;
        }
        // rescale running O
#pragma unroll
        for (int nf = 0; nf < 4; ++nf)
#pragma unroll
            for (int r = 0; r < 4; ++r) acco[nf][r] *= al[r];
        // PV on buffer cur (Ps wave-local: in-order DS per wave, no barrier)
#pragma unroll
        for (int kk = 0; kk < 2; ++kk) {
            bf16x8 ap = *(const bf16x8*)(&QPs[wave * 16 + llo][kk * 32 + lhi * 8]);
#pragma unroll
            for (int nf = 0; nf < 4; ++nf) {
                bf16x8 bv2 = *(const bf16x8*)(&Vt[cur][nf * 16 + llo][kk * 32 + lhi * 8]);
                acco[nf] = mfma16(ap, bv2, acco[nf]);
            }
        }
        // 6) write next-tile K/V into buffer cur^1
        if (it < 7) {
            *(bf16x8*)(&Ks[cur ^ 1][sr0][sc0])      = k0;
            *(bf16x8*)(&Ks[cur ^ 1][sr0 + 32][sc0]) = k1;
#pragma unroll
            for (int jj = 0; jj < 8; ++jj) {
                Vt[cur ^ 1][sc0 + jj][sr0]      = v0[jj];
                Vt[cur ^ 1][sc0 + jj][sr0 + 32] = v1[jj];
            }
        }
        // 7) single barrier per tile
        __syncthreads();
    }
#pragma unroll
    for (int nf = 0; nf < 4; ++nf) {
#pragma unroll
        for (int r = 0; r < 4; ++r) {
            int lr = wave * 16 + lhi * 4 + r;
            float oo = acco[nf][r] / l_reg[r];
            o[obase + (size_t)(qt * 64 + lr) * Hc + nf * 16 + llo] = (__bf16)oo;
        }
    }
}

// ---------------- orchestration ----------------
extern "C" void kernel_launch(void* const* d_in, const int* in_sizes, int n_in,
                              void* d_out, int out_size, void* d_ws, size_t ws_size,
                              hipStream_t stream)
{
    const float* x     = (const float*)d_in[0];
    const float* abias = (const float*)d_in[1];
    const float* ln1g  = (const float*)d_in[2];
    const float* ln1b  = (const float*)d_in[3];
    const float* wq    = (const float*)d_in[4];
    const float* bq    = (const float*)d_in[5];
    const float* wk    = (const float*)d_in[6];
    const float* bk    = (const float*)d_in[7];
    const float* wv    = (const float*)d_in[8];
    const float* bv    = (const float*)d_in[9];
    const float* wo    = (const float*)d_in[10];
    const float* bo    = (const float*)d_in[11];
    const float* ln2g  = (const float*)d_in[12];
    const float* ln2b  = (const float*)d_in[13];
    const float* w1    = (const float*)d_in[14];
    const float* b1    = (const float*)d_in[15];
    const float* w2    = (const float*)d_in[16];
    const float* b2    = (const float*)d_in[17];
    const float* flng  = (const float*)d_in[18];
    const float* flnb  = (const float*)d_in[19];

    float* h = (float*)d_out;                       // residual stream
    __bf16* y    = (__bf16*)d_ws;                   // [MR,768]
    __bf16* qkv  = y   + (size_t)MR * Hc;           // [MR,2304]
    __bf16* ob   = qkv + (size_t)MR * QS;           // [MR,768]
    __bf16* fb   = ob  + (size_t)MR * Hc;           // [MR,3072] FFN act
    __bf16* w1t  = fb  + (size_t)MR * FFc;          // [3072,768]
    __bf16* w2t  = w1t + (size_t)FFc * Hc;          // [768,3072]
    float*  bqkv = (float*)(w2t + (size_t)Hc * FFc);// [2304]
    // alias (dead before FFN act is written): QKV + O weights inside fb region
    __bf16* wqkvt = fb;                             // [2304,768]
    __bf16* wot   = fb + (size_t)QS * Hc;           // [768,768]

    hipMemcpyAsync(h, x, (size_t)MR * Hc * sizeof(float), hipMemcpyDeviceToDevice, stream);

    dim3 blk(256);
    dim3 gLN(MR / 4);
    dim3 gQKV(QS / 128, MR / 128);   // (18,64) = 1152 blocks
    dim3 gP64(Hc / 64, MR / 128);    // (12,64) = 768 blocks
    dim3 gF(FFc / 128, MR / 128);    // (24,64) = 1536 blocks
    dim3 gA(Bc * NHc, Sc / 64);      // (192,8)
    dim3 gPrep(6921);                // fused weight prep

    for (int l = 0; l < Lc; ++l) {
        const float* wq_l = wq + (size_t)l * Hc * Hc;
        const float* wk_l = wk + (size_t)l * Hc * Hc;
        const float* wv_l = wv + (size_t)l * Hc * Hc;
        const float* wo_l = wo + (size_t)l * Hc * Hc;
        const float* w1_l = w1 + (size_t)l * Hc * FFc;
        const float* w2_l = w2 + (size_t)l * FFc * Hc;

        prep_k<<<gPrep, blk, 0, stream>>>(wq_l, wk_l, wv_l, wo_l, w1_l, w2_l,
                                          bq + l * Hc, bk + l * Hc, bv + l * Hc,
                                          wqkvt, wot, w1t, w2t, bqkv);

        ln_k<false><<<gLN, blk, 0, stream>>>(h, ln1g + l * Hc, ln1b + l * Hc, y, nullptr);
        gemm2_k<0, false><<<gQKV, blk, 0, stream>>>(y, wqkvt, bqkv, nullptr, nullptr, qkv, MR, QS, Hc);
        attn_k<<<gA, blk, 0, stream>>>(qkv, qkv + Hc, qkv + 2 * Hc, abias, ob);
        gemm3_k<<<gP64, blk, 0, stream>>>(ob, wot, bo + l * Hc, h, h, MR, Hc, Hc);
        ln_k<false><<<gLN, blk, 0, stream>>>(h, ln2g + l * Hc, ln2b + l * Hc, y, nullptr);
        gemm2_k<1, false><<<gF, blk, 0, stream>>>(y, w1t, b1 + l * FFc, nullptr, nullptr, fb, MR, FFc, Hc);
        gemm3_k<<<gP64, blk, 0, stream>>>(fb, w2t, b2 + l * Hc, h, h, MR, Hc, FFc);
    }
    ln_k<true><<<gLN, blk, 0, stream>>>(h, flng, flnb, nullptr, h);
}